// Round 1
// baseline (1948.352 us; speedup 1.0000x reference)
//
#include <hip/hip_runtime.h>
#include <hip/hip_bf16.h>
#include <math.h>

#define N_NODES 30000
#define DEG 10
#define IN_DIM 3000
#define DEG_DIM 512
#define HID 512
#define OUT_DIM 30
#define PRED 20

typedef __attribute__((ext_vector_type(8))) short short8;
typedef __attribute__((ext_vector_type(8))) unsigned short ushort8;
typedef __attribute__((ext_vector_type(4))) float f32x4;

__device__ __forceinline__ unsigned short f2bf(float f) {
  unsigned int u = __builtin_bit_cast(unsigned int, f);
  u += 0x7FFFu + ((u >> 16) & 1u);   // RTNE
  return (unsigned short)(u >> 16);
}

// ---------------------------------------------------------------------------
// MFMA GEMM: C[M,N] = act(A[M,K] @ B[K,N] + bias)
//   A, B are f32 in memory, converted to bf16 while staging into LDS.
//   BTRANS: B[k][n] = Bt[n][k]  (Bt row-major, ld = ldb)
//   ACT: 0 = none, 1 = ELU
// Tile 128x128x32, 256 threads (4 waves as 2x2, each 64x64 = 4x4 frags).
// ---------------------------------------------------------------------------
template<bool BTRANS, bool HASBIAS, int ACT>
__launch_bounds__(256)
__global__ void gemm_mfma(const float* __restrict__ A, int lda,
                          const float* __restrict__ B, int ldb,
                          const float* __restrict__ bias,
                          float* __restrict__ C, int ldc,
                          int M, int N, int K) {
  constexpr int BM = 128, BN = 128, BK = 32;
  constexpr int LDP = BK + 8;            // padded row: 40 ushorts = 80B
  __shared__ unsigned short As[BM][LDP]; // [m][k]
  __shared__ unsigned short Bs[BN][LDP]; // transposed: [n][k]

  const int tid  = threadIdx.x;
  const int bm   = blockIdx.y * BM;
  const int bn   = blockIdx.x * BN;
  const int wid  = tid >> 6;
  const int lane = tid & 63;
  const int wm   = (wid >> 1) * 64;
  const int wn   = (wid & 1) * 64;
  const int r0   = lane & 15;
  const int k8   = lane >> 4;            // 0..3, k-offset = k8*8

  f32x4 acc[4][4];
  #pragma unroll
  for (int i = 0; i < 4; ++i)
    #pragma unroll
    for (int j = 0; j < 4; ++j)
      acc[i][j] = (f32x4){0.f, 0.f, 0.f, 0.f};

  // staging assignments
  const int arow = tid >> 1;             // 0..127
  const int aseg = (tid & 1) * 16;       // k offset 0 / 16
  const int brow = tid & 127;            // n within tile
  const int bseg = (tid >> 7) * 16;      // k offset 0 / 16

  for (int k0 = 0; k0 < K; k0 += BK) {
    // ---- stage A tile: A[bm+arow][k0+aseg .. +15] -> As ----
    {
      const int gr = bm + arow;
      float v[16];
      if (gr < M && (k0 + aseg + 16) <= K) {
        const float4* p = (const float4*)(A + (size_t)gr * lda + k0 + aseg);
        #pragma unroll
        for (int q = 0; q < 4; ++q) {
          float4 t = p[q];
          v[4*q+0] = t.x; v[4*q+1] = t.y; v[4*q+2] = t.z; v[4*q+3] = t.w;
        }
      } else {
        #pragma unroll
        for (int j = 0; j < 16; ++j) {
          int kk = k0 + aseg + j;
          v[j] = (gr < M && kk < K) ? A[(size_t)gr * lda + kk] : 0.f;
        }
      }
      ushort8 u0, u1;
      #pragma unroll
      for (int j = 0; j < 8; ++j) { u0[j] = f2bf(v[j]); u1[j] = f2bf(v[8 + j]); }
      *(ushort8*)&As[arow][aseg]     = u0;
      *(ushort8*)&As[arow][aseg + 8] = u1;
    }
    // ---- stage B tile (transposed into LDS): Bs[n][k] ----
    {
      const int gn = bn + brow;
      float v[16];
      if constexpr (BTRANS) {
        if (gn < N && (k0 + bseg + 16) <= K) {
          const float4* p = (const float4*)(B + (size_t)gn * ldb + k0 + bseg);
          #pragma unroll
          for (int q = 0; q < 4; ++q) {
            float4 t = p[q];
            v[4*q+0] = t.x; v[4*q+1] = t.y; v[4*q+2] = t.z; v[4*q+3] = t.w;
          }
        } else {
          #pragma unroll
          for (int j = 0; j < 16; ++j) {
            int kk = k0 + bseg + j;
            v[j] = (gn < N && kk < K) ? B[(size_t)gn * ldb + kk] : 0.f;
          }
        }
      } else {
        #pragma unroll
        for (int j = 0; j < 16; ++j) {
          int kk = k0 + bseg + j;
          v[j] = (gn < N && kk < K) ? B[(size_t)kk * ldb + gn] : 0.f;
        }
      }
      ushort8 u0, u1;
      #pragma unroll
      for (int j = 0; j < 8; ++j) { u0[j] = f2bf(v[j]); u1[j] = f2bf(v[8 + j]); }
      *(ushort8*)&Bs[brow][bseg]     = u0;
      *(ushort8*)&Bs[brow][bseg + 8] = u1;
    }
    __syncthreads();

    // ---- fragments + MFMA ----
    short8 af[4], bf[4];
    #pragma unroll
    for (int f = 0; f < 4; ++f)
      af[f] = *(const short8*)&As[wm + f * 16 + r0][k8 * 8];
    #pragma unroll
    for (int f = 0; f < 4; ++f)
      bf[f] = *(const short8*)&Bs[wn + f * 16 + r0][k8 * 8];
    #pragma unroll
    for (int i = 0; i < 4; ++i)
      #pragma unroll
      for (int j = 0; j < 4; ++j)
        acc[i][j] = __builtin_amdgcn_mfma_f32_16x16x32_bf16(af[i], bf[j], acc[i][j], 0, 0, 0);
    __syncthreads();
  }

  // ---- epilogue: D row = (lane>>4)*4 + q, col = lane&15 ----
  #pragma unroll
  for (int i = 0; i < 4; ++i) {
    const int gm0 = bm + wm + i * 16 + (lane >> 4) * 4;
    #pragma unroll
    for (int j = 0; j < 4; ++j) {
      const int gn = bn + wn + j * 16 + r0;
      if (gn >= N) continue;
      float bv = 0.f;
      if constexpr (HASBIAS) bv = bias[gn];
      #pragma unroll
      for (int q = 0; q < 4; ++q) {
        const int gm = gm0 + q;
        if (gm < M) {
          float val = acc[i][j][q] + bv;
          if constexpr (ACT == 1) val = val > 0.f ? val : expm1f(val);
          C[(size_t)gm * ldc + gn] = val;
        }
      }
    }
  }
}

// ---------------------------------------------------------------------------
// a1s[i] = x1[i,:] . att_src ; a1d[i] = x1[i,:] . att_dst   (wave per row)
// ---------------------------------------------------------------------------
__global__ void row_dots(const float* __restrict__ x,
                         const float* __restrict__ vs, const float* __restrict__ vd,
                         float* __restrict__ os, float* __restrict__ od) {
  const int row  = blockIdx.x * 4 + (threadIdx.x >> 6);
  const int lane = threadIdx.x & 63;
  const float4* xr = (const float4*)(x + (size_t)row * HID) + lane * 2;
  const float4* s4 = (const float4*)vs + lane * 2;
  const float4* d4 = (const float4*)vd + lane * 2;
  float4 x0 = xr[0], x1 = xr[1];
  float4 s0 = s4[0], s1 = s4[1];
  float4 dd0 = d4[0], dd1 = d4[1];
  float ds = x0.x*s0.x + x0.y*s0.y + x0.z*s0.z + x0.w*s0.w
           + x1.x*s1.x + x1.y*s1.y + x1.z*s1.z + x1.w*s1.w;
  float dv = x0.x*dd0.x + x0.y*dd0.y + x0.z*dd0.z + x0.w*dd0.w
           + x1.x*dd1.x + x1.y*dd1.y + x1.z*dd1.z + x1.w*dd1.w;
  #pragma unroll
  for (int off = 32; off > 0; off >>= 1) {
    ds += __shfl_xor(ds, off);
    dv += __shfl_xor(dv, off);
  }
  if (lane == 0) { os[row] = ds; od[row] = dv; }
}

// ---------------------------------------------------------------------------
// Attention aggregate + ELU, wave per node. Edges for node i are i*DEG..+DEG.
// out[i,:] = elu( sum_j softmax_j(lrelu(a_s[src_j]+a_d[i])) * x[src_j,:] )
// ---------------------------------------------------------------------------
__global__ void attn_agg(const float* __restrict__ x, const int* __restrict__ src,
                         const float* __restrict__ a_s, const float* __restrict__ a_d,
                         float* __restrict__ out) {
  const int node = blockIdx.x * 4 + (threadIdx.x >> 6);
  const int lane = threadIdx.x & 63;
  int   sj[DEG];
  float e[DEG];
  const float ad = a_d[node];
  float m = -1e30f;
  #pragma unroll
  for (int j = 0; j < DEG; ++j) {
    sj[j] = src[node * DEG + j];
    float v = a_s[sj[j]] + ad;
    v = v > 0.f ? v : 0.2f * v;
    e[j] = v;
    m = fmaxf(m, v);
  }
  float denom = 0.f;
  #pragma unroll
  for (int j = 0; j < DEG; ++j) { e[j] = expf(e[j] - m); denom += e[j]; }
  const float inv = 1.f / denom;
  float4 a0 = make_float4(0,0,0,0), a1 = make_float4(0,0,0,0);
  #pragma unroll
  for (int j = 0; j < DEG; ++j) {
    const float a = e[j] * inv;
    const float4* r = (const float4*)(x + (size_t)sj[j] * HID) + lane * 2;
    float4 v0 = r[0], v1 = r[1];
    a0.x += a * v0.x; a0.y += a * v0.y; a0.z += a * v0.z; a0.w += a * v0.w;
    a1.x += a * v1.x; a1.y += a * v1.y; a1.z += a * v1.z; a1.w += a * v1.w;
  }
  a0.x = a0.x > 0.f ? a0.x : expm1f(a0.x);
  a0.y = a0.y > 0.f ? a0.y : expm1f(a0.y);
  a0.z = a0.z > 0.f ? a0.z : expm1f(a0.z);
  a0.w = a0.w > 0.f ? a0.w : expm1f(a0.w);
  a1.x = a1.x > 0.f ? a1.x : expm1f(a1.x);
  a1.y = a1.y > 0.f ? a1.y : expm1f(a1.y);
  a1.z = a1.z > 0.f ? a1.z : expm1f(a1.z);
  a1.w = a1.w > 0.f ? a1.w : expm1f(a1.w);
  float4* o = (float4*)(out + (size_t)node * HID) + lane * 2;
  o[0] = a0; o[1] = a1;
}

// ---------------------------------------------------------------------------
// h2[M,30] = h1[M,512] @ W2[512,30]   (thread per output)
// ---------------------------------------------------------------------------
__global__ void h2_kernel(const float* __restrict__ h1, const float* __restrict__ W2,
                          float* __restrict__ h2) {
  const int idx = blockIdx.x * blockDim.x + threadIdx.x;
  if (idx >= N_NODES * OUT_DIM) return;
  const int i = idx / OUT_DIM, j = idx - i * OUT_DIM;
  const float* a = h1 + (size_t)i * HID;
  float acc = 0.f;
  #pragma unroll 8
  for (int k = 0; k < HID; ++k) acc = fmaf(a[k], W2[k * OUT_DIM + j], acc);
  h2[idx] = acc;
}

// ---------------------------------------------------------------------------
// x3[M,512] = h2[M,30] @ W2[512,30]^T   (thread per output)
// ---------------------------------------------------------------------------
__global__ void x3_kernel(const float* __restrict__ h2, const float* __restrict__ W2,
                          float* __restrict__ x3) {
  const int idx = blockIdx.x * blockDim.x + threadIdx.x;
  if (idx >= N_NODES * HID) return;
  const int i = idx >> 9, n = idx & 511;
  const float* hr = h2 + (size_t)i * OUT_DIM;
  const float* wr = W2 + (size_t)n * OUT_DIM;
  float acc = 0.f;
  #pragma unroll
  for (int k = 0; k < OUT_DIM; ++k) acc = fmaf(hr[k], wr[k], acc);
  x3[idx] = acc;
}

// ---------------------------------------------------------------------------
// out[i,:] = log_softmax(h2[i,:] @ W_pred + b_pred)   (thread per row)
// ---------------------------------------------------------------------------
__global__ void pred_kernel(const float* __restrict__ h2, const float* __restrict__ Wp,
                            const float* __restrict__ bp, float* __restrict__ out) {
  const int i = blockIdx.x * blockDim.x + threadIdx.x;
  if (i >= N_NODES) return;
  float h[OUT_DIM];
  #pragma unroll
  for (int k = 0; k < OUT_DIM; ++k) h[k] = h2[(size_t)i * OUT_DIM + k];
  float p[PRED];
  float m = -1e30f;
  #pragma unroll
  for (int j = 0; j < PRED; ++j) {
    float acc = bp[j];
    #pragma unroll
    for (int k = 0; k < OUT_DIM; ++k) acc = fmaf(h[k], Wp[k * PRED + j], acc);
    p[j] = acc;
    m = fmaxf(m, acc);
  }
  float s = 0.f;
  #pragma unroll
  for (int j = 0; j < PRED; ++j) s += expf(p[j] - m);
  const float lse = m + logf(s);
  #pragma unroll
  for (int j = 0; j < PRED; ++j) out[(size_t)i * PRED + j] = p[j] - lse;
}

// ---------------------------------------------------------------------------
extern "C" void kernel_launch(void* const* d_in, const int* in_sizes, int n_in,
                              void* d_out, int out_size, void* d_ws, size_t ws_size,
                              hipStream_t stream) {
  const float* features = (const float*)d_in[0];
  const int*   edge_idx = (const int*)d_in[1];
  const float* W_enc    = (const float*)d_in[2];
  const float* b_enc    = (const float*)d_in[3];
  const float* W1       = (const float*)d_in[4];
  const float* att_s    = (const float*)d_in[5];
  const float* att_d    = (const float*)d_in[6];
  const float* W2       = (const float*)d_in[7];
  const float* W_pred   = (const float*)d_in[8];
  const float* b_pred   = (const float*)d_in[9];
  const float* W_dec    = (const float*)d_in[10];
  const float* b_dec    = (const float*)d_in[11];

  float* out_h2   = (float*)d_out;                                  // [30000,30]
  float* out_dec  = out_h2 + (size_t)N_NODES * OUT_DIM;             // [30000,3000]
  float* out_pred = out_h2 + (size_t)N_NODES * OUT_DIM
                           + (size_t)N_NODES * IN_DIM;              // [30000,20]

  const size_t S = (size_t)N_NODES * HID;
  float* bufA = (float*)d_ws;       // de -> h1 -> h3
  float* bufB = bufA + S;           // x1 -> x3 -> elu(h4)
  float* a1s  = bufB + S;
  float* a1d  = a1s + N_NODES;

  const int* src = edge_idx;        // row 0 of edge_index = src

  const dim3 blk(256);
  const int mtiles = (N_NODES + 127) / 128;   // 235

  // 1. de = features @ W_enc + b_enc             -> bufA
  gemm_mfma<false, true, 0><<<dim3((DEG_DIM + 127) / 128, mtiles), blk, 0, stream>>>(
      features, IN_DIM, W_enc, DEG_DIM, b_enc, bufA, DEG_DIM, N_NODES, DEG_DIM, IN_DIM);
  // 2. x1 = de @ W1                              -> bufB
  gemm_mfma<false, false, 0><<<dim3((HID + 127) / 128, mtiles), blk, 0, stream>>>(
      bufA, DEG_DIM, W1, HID, nullptr, bufB, HID, N_NODES, HID, DEG_DIM);
  // 3. a1s, a1d
  row_dots<<<dim3(N_NODES / 4), blk, 0, stream>>>(bufB, att_s, att_d, a1s, a1d);
  // 4. h1 = elu(agg(x1))                         -> bufA
  attn_agg<<<dim3(N_NODES / 4), blk, 0, stream>>>(bufB, src, a1s, a1d, bufA);
  // 5. h2 = h1 @ W2                              -> out_h2
  h2_kernel<<<dim3((N_NODES * OUT_DIM + 255) / 256), blk, 0, stream>>>(bufA, W2, out_h2);
  // 6. log_softmax(h2 @ W_pred + b_pred)         -> out_pred
  pred_kernel<<<dim3((N_NODES + 255) / 256), blk, 0, stream>>>(out_h2, W_pred, b_pred, out_pred);
  // 7. x3 = h2 @ W2^T                            -> bufB
  x3_kernel<<<dim3((N_NODES * HID + 255) / 256), blk, 0, stream>>>(out_h2, W2, bufB);
  // 8. h3 = elu(agg(x3))                         -> bufA
  attn_agg<<<dim3(N_NODES / 4), blk, 0, stream>>>(bufB, src, a1s, a1d, bufA);
  // 9. elu(h4) = elu(h3 @ W1^T)                  -> bufB
  gemm_mfma<true, false, 1><<<dim3((HID + 127) / 128, mtiles), blk, 0, stream>>>(
      bufA, HID, W1, HID, nullptr, bufB, HID, N_NODES, HID, HID);
  // 10. out = elu(h4) @ W_dec + b_dec            -> out_dec
  gemm_mfma<false, true, 0><<<dim3((IN_DIM + 127) / 128, mtiles), blk, 0, stream>>>(
      bufB, HID, W_dec, IN_DIM, b_dec, out_dec, IN_DIM, N_NODES, IN_DIM, HID);
}